// Round 3
// baseline (160.352 us; speedup 1.0000x reference)
//
#include <hip/hip_runtime.h>

#define DIM 4096
#define R 8

// ws layout: T (4096x8 floats) at ws[0..]
// S = G^{-1} is now per-block (LDS) — no tiny serial kernel in the chain.

// ---------------------------------------------------------------------------
// K1': fused Gram + inverse + T.  1024 blocks x 256 threads, 4 W-rows each.
// Every block redundantly computes G = A^T A (36-entry triangle) and
// S = G^{-1} (Gauss-Jordan on wave 0); A is L2/L3-hot after the first blocks.
// Then T[row][:] = 2 * (W[row,:] @ A) @ S for its 4 rows.
// ---------------------------------------------------------------------------
__global__ __launch_bounds__(256) void t_kernel(const float* __restrict__ W,
                                                const float* __restrict__ A,
                                                float* __restrict__ T) {
    __shared__ float red[4][36];  // per-wave partials: Gram triangle, then p
    __shared__ float sb[64];      // S = G^{-1} (8x8)
    __shared__ float pb[32];      // reduced p

    const int t = threadIdx.x;
    const int wave = t >> 6, lane = t & 63;
    const int row0 = blockIdx.x * 4;
    const float4* W4 = (const float4*)W;
    const float4* A4 = (const float4*)A;

    // ---- Gram phase: accumulate upper triangle (a<=b), 36 entries
    float g[36];
#pragma unroll
    for (int i = 0; i < 36; ++i) g[i] = 0.f;

#pragma unroll
    for (int it = 0; it < DIM / 256; ++it) {
        const int j = it * 256 + t;
        float4 lo = A4[j * 2 + 0];
        float4 hi = A4[j * 2 + 1];
        float u[R] = {lo.x, lo.y, lo.z, lo.w, hi.x, hi.y, hi.z, hi.w};
        int idx = 0;
#pragma unroll
        for (int a = 0; a < R; ++a)
#pragma unroll
            for (int b = a; b < R; ++b) { g[idx] += u[a] * u[b]; ++idx; }
    }

    // wave butterfly: every lane ends with the wave's sums
#pragma unroll
    for (int i = 0; i < 36; ++i) {
        float v = g[i];
#pragma unroll
        for (int off = 32; off >= 1; off >>= 1) v += __shfl_xor(v, off, 64);
        g[i] = v;
    }
#pragma unroll
    for (int i = 0; i < 36; ++i)
        if (lane == i) red[wave][i] = g[i];
    __syncthreads();  // S1: red[] holds per-wave Gram triangles

    // ---- wave 0: expand triangle to 8x8, Gauss-Jordan invert -> sb
    if (wave == 0) {
        const int r_ = lane >> 3, c_ = lane & 7;
        const int a = (r_ < c_) ? r_ : c_;
        const int b = (r_ < c_) ? c_ : r_;
        const int tidx = a * 8 + b - (a * (a + 1)) / 2;
        float M = red[0][tidx] + red[1][tidx] + red[2][tidx] + red[3][tidx];
        float E = (r_ == c_) ? 1.f : 0.f;
        // no pivoting: G is SPD, kappa ~ 1
#pragma unroll
        for (int k = 0; k < R; ++k) {
            float piv  = __shfl(M, k * 8 + k, 64);
            float pinv = 1.0f / piv;
            float Mkc  = __shfl(M, k * 8 + c_, 64) * pinv;
            float Ekc  = __shfl(E, k * 8 + c_, 64) * pinv;
            float Mrk  = __shfl(M, r_ * 8 + k, 64);
            bool  isk  = (r_ == k);
            M = isk ? Mkc : (M - Mrk * Mkc);
            E = isk ? Ekc : (E - Mrk * Ekc);
        }
        sb[lane] = E;
    }

    // ---- dot phase (all waves): p[r][k] = W[row0+r,:] @ A[:,k]
    float p[4][R];
#pragma unroll
    for (int r = 0; r < 4; ++r)
#pragma unroll
        for (int k = 0; k < R; ++k) p[r][k] = 0.f;

#pragma unroll
    for (int c = 0; c < 4; ++c) {
        float4 w[4];
#pragma unroll
        for (int r = 0; r < 4; ++r)
            w[r] = W4[(size_t)(row0 + r) * (DIM / 4) + c * 256 + t];
#pragma unroll
        for (int jj = 0; jj < 4; ++jj) {
            const int j = (c * 256 + t) * 4 + jj;
            float4 alo = A4[j * 2 + 0];
            float4 ahi = A4[j * 2 + 1];
#pragma unroll
            for (int r = 0; r < 4; ++r) {
                const float wv = ((const float*)&w[r])[jj];
                p[r][0] += wv * alo.x; p[r][1] += wv * alo.y;
                p[r][2] += wv * alo.z; p[r][3] += wv * alo.w;
                p[r][4] += wv * ahi.x; p[r][5] += wv * ahi.y;
                p[r][6] += wv * ahi.z; p[r][7] += wv * ahi.w;
            }
        }
    }

#pragma unroll
    for (int r = 0; r < 4; ++r)
#pragma unroll
        for (int k = 0; k < R; ++k) {
            float v = p[r][k];
#pragma unroll
            for (int off = 32; off >= 1; off >>= 1) v += __shfl_xor(v, off, 64);
            p[r][k] = v;
        }

    __syncthreads();  // S2: wave 0 done reading red[], sb[] written

#pragma unroll
    for (int i = 0; i < 32; ++i)
        if (lane == i) red[wave][i] = p[i / R][i % R];
    __syncthreads();  // S3

    if (t < 32) pb[t] = red[0][t] + red[1][t] + red[2][t] + red[3][t];
    __syncthreads();  // S4

    if (t < 32) {
        const int r = t >> 3, k = t & 7;
        float a = 0.f;
#pragma unroll
        for (int m = 0; m < R; ++m) a += sb[k * 8 + m] * pb[r * 8 + m];
        T[(size_t)(row0 + r) * R + k] = 2.0f * a;
    }
}

// ---------------------------------------------------------------------------
// K2: out = W - T . A^T.  Pure streaming, no barriers. Tile = 32 rows x 256
// cols; 2048 blocks x 256 threads; each thread: A-fragment in regs, 8 rows.
// ---------------------------------------------------------------------------
__global__ __launch_bounds__(256) void apply_kernel(const float* __restrict__ W,
                                                    const float* __restrict__ A,
                                                    const float* __restrict__ T,
                                                    float* __restrict__ out) {
    const int t = threadIdx.x;
    const int wave = t >> 6, lane = t & 63;
    const int bid = blockIdx.x;
    const int tr = bid >> 4;        // 128 row-tiles of 32
    const int tc = bid & 15;        // 16 col-tiles of 256
    const int c4 = tc * 64 + lane;  // float4 column index [0,1024)

    const float4* A4 = (const float4*)A;
    const float4* W4 = (const float4*)W;
    const float4* T4 = (const float4*)T;
    float4* O4 = (float4*)out;

    float4 alo[4], ahi[4];
#pragma unroll
    for (int jj = 0; jj < 4; ++jj) {
        const int j = c4 * 4 + jj;
        alo[jj] = A4[j * 2 + 0];
        ahi[jj] = A4[j * 2 + 1];
    }

    const int row0 = tr * 32 + wave * 8;
#pragma unroll
    for (int rr = 0; rr < 8; ++rr) {
        const int row = row0 + rr;
        float4 t01 = T4[(size_t)row * 2 + 0];   // T[row][0..3]
        float4 t23 = T4[(size_t)row * 2 + 1];   // T[row][4..7]
        float4 w4 = W4[(size_t)row * (DIM / 4) + c4];
        float o[4];
#pragma unroll
        for (int jj = 0; jj < 4; ++jj) {
            float d = t01.x * alo[jj].x + t01.y * alo[jj].y +
                      t01.z * alo[jj].z + t01.w * alo[jj].w +
                      t23.x * ahi[jj].x + t23.y * ahi[jj].y +
                      t23.z * ahi[jj].z + t23.w * ahi[jj].w;
            o[jj] = ((const float*)&w4)[jj] - d;
        }
        O4[(size_t)row * (DIM / 4) + c4] = make_float4(o[0], o[1], o[2], o[3]);
    }
}

extern "C" void kernel_launch(void* const* d_in, const int* in_sizes, int n_in,
                              void* d_out, int out_size, void* d_ws, size_t ws_size,
                              hipStream_t stream) {
    const float* W = (const float*)d_in[0];    // [4096][4096] f32
    const float* A = (const float*)d_in[1];    // [4096][8]    f32
    float* out = (float*)d_out;                // [4096][4096] f32
    float* T = (float*)d_ws;                   // 4096*8 floats scratch

    t_kernel<<<DIM / 4, 256, 0, stream>>>(W, A, T);
    apply_kernel<<<2048, 256, 0, stream>>>(W, A, T, out);
}

// Round 4
// 84.887 us; speedup vs baseline: 1.8890x; 1.8890x over previous
//
#include <hip/hip_runtime.h>

#define DIM 4096
#define R 8

// ws layout: Sinv (64 floats) at ws[0]; P = W@A (4096x8 floats) at ws+64
#define P_OFF 64

// ---------------------------------------------------------------------------
// Per-wave Gram accumulation (block 0 only). Wave WAVE owns triangle rows
// a = WAVE and a = WAVE+4 (<=12 accumulators). Each wave traverses ALL of A
// (L2-hot, 128 KB). After butterfly, lane 0 deposits into gsh[a*8+b].
// ---------------------------------------------------------------------------
template <int WAVE>
__device__ inline void gram_wave(const float4* __restrict__ A4, int lane,
                                 float* __restrict__ gsh) {
    constexpr int NA = 8 - WAVE;       // entries for a = WAVE
    constexpr int NB = 4 - WAVE;       // entries for a = WAVE+4
    float g[NA + NB];
#pragma unroll
    for (int i = 0; i < NA + NB; ++i) g[i] = 0.f;

#pragma unroll 8
    for (int it = 0; it < DIM / 64; ++it) {
        const int j = it * 64 + lane;
        float4 lo = A4[j * 2 + 0];
        float4 hi = A4[j * 2 + 1];
        float u[R] = {lo.x, lo.y, lo.z, lo.w, hi.x, hi.y, hi.z, hi.w};
#pragma unroll
        for (int b = WAVE; b < 8; ++b) g[b - WAVE] += u[WAVE] * u[b];
#pragma unroll
        for (int b = WAVE + 4; b < 8; ++b) g[NA + b - WAVE - 4] += u[WAVE + 4] * u[b];
    }

#pragma unroll
    for (int i = 0; i < NA + NB; ++i) {
        float v = g[i];
#pragma unroll
        for (int off = 32; off >= 1; off >>= 1) v += __shfl_xor(v, off, 64);
        g[i] = v;
    }
    if (lane == 0) {
#pragma unroll
        for (int b = WAVE; b < 8; ++b) gsh[WAVE * 8 + b] = g[b - WAVE];
#pragma unroll
        for (int b = WAVE + 4; b < 8; ++b) gsh[(WAVE + 4) * 8 + b] = g[NA + b - WAVE - 4];
    }
}

// ---------------------------------------------------------------------------
// K1: P = W @ A (raw dots). Block 0 additionally: Gram + Gauss-Jordan -> Sinv.
// 1024 blocks x 256 threads, 4 W-rows per block.
// ---------------------------------------------------------------------------
__global__ __launch_bounds__(256, 4) void dot_gram_kernel(const float* __restrict__ W,
                                                          const float* __restrict__ A,
                                                          float* __restrict__ Sinv,
                                                          float* __restrict__ P) {
    __shared__ float red[4][32];
    __shared__ float gsh[64];

    const int t = threadIdx.x;
    const int wave = t >> 6, lane = t & 63;
    const int row0 = blockIdx.x * 4;
    const float4* W4 = (const float4*)W;
    const float4* A4 = (const float4*)A;

    if (blockIdx.x == 0) {
        switch (wave) {
            case 0: gram_wave<0>(A4, lane, gsh); break;
            case 1: gram_wave<1>(A4, lane, gsh); break;
            case 2: gram_wave<2>(A4, lane, gsh); break;
            default: gram_wave<3>(A4, lane, gsh); break;
        }
        __syncthreads();  // gsh complete
        if (wave == 0) {
            const int r_ = lane >> 3, c_ = lane & 7;
            const int a = (r_ < c_) ? r_ : c_;
            const int b = (r_ < c_) ? c_ : r_;
            float M = gsh[a * 8 + b];
            float E = (r_ == c_) ? 1.f : 0.f;
            // Gauss-Jordan, no pivoting (G is SPD, kappa ~ 1)
#pragma unroll
            for (int k = 0; k < R; ++k) {
                float piv  = __shfl(M, k * 8 + k, 64);
                float pinv = 1.0f / piv;
                float Mkc  = __shfl(M, k * 8 + c_, 64) * pinv;
                float Ekc  = __shfl(E, k * 8 + c_, 64) * pinv;
                float Mrk  = __shfl(M, r_ * 8 + k, 64);
                bool  isk  = (r_ == k);
                M = isk ? Mkc : (M - Mrk * Mkc);
                E = isk ? Ekc : (E - Mrk * Ekc);
            }
            Sinv[lane] = E;
        }
    }

    // ---- dot phase (all blocks): p[r][k] = W[row0+r,:] @ A[:,k]
    float p[4][R];
#pragma unroll
    for (int r = 0; r < 4; ++r)
#pragma unroll
        for (int k = 0; k < R; ++k) p[r][k] = 0.f;

#pragma unroll
    for (int c = 0; c < 4; ++c) {
        float4 w[4];
#pragma unroll
        for (int r = 0; r < 4; ++r)
            w[r] = W4[(size_t)(row0 + r) * (DIM / 4) + c * 256 + t];
#pragma unroll
        for (int jj = 0; jj < 4; ++jj) {
            const int j = (c * 256 + t) * 4 + jj;
            float4 alo = A4[j * 2 + 0];
            float4 ahi = A4[j * 2 + 1];
#pragma unroll
            for (int r = 0; r < 4; ++r) {
                const float wv = ((const float*)&w[r])[jj];
                p[r][0] += wv * alo.x; p[r][1] += wv * alo.y;
                p[r][2] += wv * alo.z; p[r][3] += wv * alo.w;
                p[r][4] += wv * ahi.x; p[r][5] += wv * ahi.y;
                p[r][6] += wv * ahi.z; p[r][7] += wv * ahi.w;
            }
        }
    }

#pragma unroll
    for (int r = 0; r < 4; ++r)
#pragma unroll
        for (int k = 0; k < R; ++k) {
            float v = p[r][k];
#pragma unroll
            for (int off = 32; off >= 1; off >>= 1) v += __shfl_xor(v, off, 64);
            p[r][k] = v;
        }

#pragma unroll
    for (int i = 0; i < 32; ++i)
        if (lane == i) red[wave][i] = p[i / R][i % R];
    __syncthreads();

    if (t < 32) {
        float v = red[0][t] + red[1][t] + red[2][t] + red[3][t];
        P[(size_t)(row0 + (t >> 3)) * R + (t & 7)] = v;
    }
}

// ---------------------------------------------------------------------------
// K2: out = W - (2 P Sinv) . A^T.  2048 blocks x 256 threads.
// One barrier: 256 t-values (one per thread) into LDS, then pure stream.
// ---------------------------------------------------------------------------
__global__ __launch_bounds__(256, 4) void apply_kernel(const float* __restrict__ W,
                                                       const float* __restrict__ A,
                                                       const float* __restrict__ Sinv,
                                                       const float* __restrict__ P,
                                                       float* __restrict__ out) {
    __shared__ float tsh[32][8];

    const int t = threadIdx.x;
    const int wave = t >> 6, lane = t & 63;
    const int bid = blockIdx.x;
    const int tr = bid >> 4;        // 128 row-tiles of 32
    const int tc = bid & 15;        // 16 col-tiles of 256
    const int c4 = tc * 64 + lane;  // float4 column index [0,1024)

    const float4* A4 = (const float4*)A;
    const float4* W4 = (const float4*)W;
    float4* O4 = (float4*)out;

    // one t-value per thread: t[r][k] = 2 * sum_m Sinv[k][m] * P[row][m]
    {
        const int r = t >> 3, k = t & 7;
        const int row = tr * 32 + r;
        float a = 0.f;
#pragma unroll
        for (int m = 0; m < R; ++m) a += Sinv[k * 8 + m] * P[(size_t)row * R + m];
        tsh[r][k] = 2.0f * a;
    }

    // A fragment for this thread's 4 columns (load before barrier to overlap)
    float4 alo[4], ahi[4];
#pragma unroll
    for (int jj = 0; jj < 4; ++jj) {
        const int j = c4 * 4 + jj;
        alo[jj] = A4[j * 2 + 0];
        ahi[jj] = A4[j * 2 + 1];
    }
    __syncthreads();

    const int lr0 = wave * 8;
#pragma unroll
    for (int rr = 0; rr < 8; ++rr) {
        const int row = tr * 32 + lr0 + rr;
        const float* tv = &tsh[lr0 + rr][0];
        float t0 = tv[0], t1 = tv[1], t2 = tv[2], t3 = tv[3];
        float t4 = tv[4], t5 = tv[5], t6 = tv[6], t7 = tv[7];
        float4 w4 = W4[(size_t)row * (DIM / 4) + c4];
        float o[4];
#pragma unroll
        for (int jj = 0; jj < 4; ++jj) {
            float d = t0 * alo[jj].x + t1 * alo[jj].y +
                      t2 * alo[jj].z + t3 * alo[jj].w +
                      t4 * ahi[jj].x + t5 * ahi[jj].y +
                      t6 * ahi[jj].z + t7 * ahi[jj].w;
            o[jj] = ((const float*)&w4)[jj] - d;
        }
        O4[(size_t)row * (DIM / 4) + c4] = make_float4(o[0], o[1], o[2], o[3]);
    }
}

extern "C" void kernel_launch(void* const* d_in, const int* in_sizes, int n_in,
                              void* d_out, int out_size, void* d_ws, size_t ws_size,
                              hipStream_t stream) {
    const float* W = (const float*)d_in[0];    // [4096][4096] f32
    const float* A = (const float*)d_in[1];    // [4096][8]    f32
    float* out = (float*)d_out;                // [4096][4096] f32
    float* Sinv = (float*)d_ws;                // 64 floats
    float* P = (float*)d_ws + P_OFF;           // 4096*8 floats

    dot_gram_kernel<<<DIM / 4, 256, 0, stream>>>(W, A, Sinv, P);
    apply_kernel<<<2048, 256, 0, stream>>>(W, A, Sinv, P, out);
}

// Round 6
// 62.610 us; speedup vs baseline: 2.5611x; 1.3558x over previous
//
#include <hip/hip_runtime.h>

#define DIM 4096
#define R 8
// ws layout: G (8x8) at ws[0..63]; P = W@A (4096x8) at ws+64
#define P_OFF 64

// ---------------------------------------------------------------------------
// K1: P = W @ A (1024 blocks, 4 rows each, full columns, plain stores) plus
// two extra blocks (1024, 1025) that compute G = A^T A rows 0..3 / 4..7 via
// an early-return path (plain stores, no atomics).
// ---------------------------------------------------------------------------
__global__ __launch_bounds__(256) void dot_kernel(const float* __restrict__ W,
                                                  const float* __restrict__ A,
                                                  float* __restrict__ G,
                                                  float* __restrict__ P) {
    __shared__ float red[4][32];
    const int t = threadIdx.x;
    const int wave = t >> 6, lane = t & 63;
    const int bid = blockIdx.x;
    const float4* W4 = (const float4*)W;
    const float4* A4 = (const float4*)A;

    if (bid >= DIM / 4) {
        // ---- Gram path: block 1024 -> G rows 0..3, block 1025 -> rows 4..7
        const int hi = (bid - DIM / 4) * 4;  // 0 or 4 (block-uniform)
        float p[4][R];
#pragma unroll
        for (int r = 0; r < 4; ++r)
#pragma unroll
            for (int k = 0; k < R; ++k) p[r][k] = 0.f;

        for (int it = 0; it < DIM / 256; ++it) {
            const int j = it * 256 + t;
            float4 alo = A4[j * 2 + 0];
            float4 ahi = A4[j * 2 + 1];
            float u[R] = {alo.x, alo.y, alo.z, alo.w, ahi.x, ahi.y, ahi.z, ahi.w};
            // wv[r] = u[hi + r] via uniform select (no runtime array index)
            float wv0 = hi ? u[4] : u[0];
            float wv1 = hi ? u[5] : u[1];
            float wv2 = hi ? u[6] : u[2];
            float wv3 = hi ? u[7] : u[3];
#pragma unroll
            for (int k = 0; k < R; ++k) {
                p[0][k] += wv0 * u[k];
                p[1][k] += wv1 * u[k];
                p[2][k] += wv2 * u[k];
                p[3][k] += wv3 * u[k];
            }
        }

#pragma unroll
        for (int r = 0; r < 4; ++r)
#pragma unroll
            for (int k = 0; k < R; ++k) {
                float v = p[r][k];
#pragma unroll
                for (int off = 32; off >= 1; off >>= 1) v += __shfl_xor(v, off, 64);
                p[r][k] = v;
            }

#pragma unroll
        for (int i = 0; i < 32; ++i)
            if (lane == i) red[wave][i] = p[i / R][i % R];
        __syncthreads();

        if (t < 32) {
            float v = red[0][t] + red[1][t] + red[2][t] + red[3][t];
            G[(hi + (t >> 3)) * 8 + (t & 7)] = v;
        }
        return;
    }

    // ---- main dot path (exact R2 structure): p[r][k] = W[row0+r,:] @ A[:,k]
    const int row0 = bid * 4;
    float p[4][R];
#pragma unroll
    for (int r = 0; r < 4; ++r)
#pragma unroll
        for (int k = 0; k < R; ++k) p[r][k] = 0.f;

#pragma unroll
    for (int c = 0; c < 4; ++c) {
        float4 w[4];
#pragma unroll
        for (int r = 0; r < 4; ++r)
            w[r] = W4[(size_t)(row0 + r) * (DIM / 4) + c * 256 + t];
#pragma unroll
        for (int jj = 0; jj < 4; ++jj) {
            const int j = (c * 256 + t) * 4 + jj;
            float4 alo = A4[j * 2 + 0];
            float4 ahi = A4[j * 2 + 1];
#pragma unroll
            for (int r = 0; r < 4; ++r) {
                const float wv = ((const float*)&w[r])[jj];
                p[r][0] += wv * alo.x; p[r][1] += wv * alo.y;
                p[r][2] += wv * alo.z; p[r][3] += wv * alo.w;
                p[r][4] += wv * ahi.x; p[r][5] += wv * ahi.y;
                p[r][6] += wv * ahi.z; p[r][7] += wv * ahi.w;
            }
        }
    }

#pragma unroll
    for (int r = 0; r < 4; ++r)
#pragma unroll
        for (int k = 0; k < R; ++k) {
            float v = p[r][k];
#pragma unroll
            for (int off = 32; off >= 1; off >>= 1) v += __shfl_xor(v, off, 64);
            p[r][k] = v;
        }

#pragma unroll
    for (int i = 0; i < 32; ++i)
        if (lane == i) red[wave][i] = p[i / R][i % R];
    __syncthreads();

    if (t < 32) {
        float v = red[0][t] + red[1][t] + red[2][t] + red[3][t];
        P[(size_t)(row0 + (t >> 3)) * R + (t & 7)] = v;
    }
}

// ---------------------------------------------------------------------------
// K2: out = W - (2 P G^{-1}) . A^T.  2048 blocks x 256 threads (R4's proven
// body). Wave 0 inverts G (8x8 Gauss-Jordan) hidden under A-fragment loads.
// ---------------------------------------------------------------------------
__global__ __launch_bounds__(256, 4) void apply_kernel(const float* __restrict__ W,
                                                       const float* __restrict__ A,
                                                       const float* __restrict__ G,
                                                       const float* __restrict__ P,
                                                       float* __restrict__ out) {
    __shared__ float sb[64];       // Sinv = G^{-1}
    __shared__ float tsh[32][8];

    const int t = threadIdx.x;
    const int wave = t >> 6, lane = t & 63;
    const int bid = blockIdx.x;
    const int tr = bid >> 4;        // 128 row-tiles of 32
    const int tc = bid & 15;        // 16 col-tiles of 256
    const int c4 = tc * 64 + lane;  // float4 column index [0,1024)

    const float4* A4 = (const float4*)A;
    const float4* W4 = (const float4*)W;
    float4* O4 = (float4*)out;

    // issue A-fragment loads first (independent, hides the GJ below)
    float4 alo[4], ahi[4];
#pragma unroll
    for (int jj = 0; jj < 4; ++jj) {
        const int j = c4 * 4 + jj;
        alo[jj] = A4[j * 2 + 0];
        ahi[jj] = A4[j * 2 + 1];
    }

    if (wave == 0) {
        const int r_ = lane >> 3, c_ = lane & 7;
        float M = G[lane];
        float E = (r_ == c_) ? 1.f : 0.f;
        // Gauss-Jordan, no pivoting (G is SPD, kappa ~ 1)
#pragma unroll
        for (int k = 0; k < R; ++k) {
            float piv  = __shfl(M, k * 8 + k, 64);
            float pinv = 1.0f / piv;
            float Mkc  = __shfl(M, k * 8 + c_, 64) * pinv;
            float Ekc  = __shfl(E, k * 8 + c_, 64) * pinv;
            float Mrk  = __shfl(M, r_ * 8 + k, 64);
            bool  isk  = (r_ == k);
            M = isk ? Mkc : (M - Mrk * Mkc);
            E = isk ? Ekc : (E - Mrk * Ekc);
        }
        sb[lane] = E;
    }
    __syncthreads();

    // one t-value per thread: t[r][k] = 2 * sum_m Sinv[k][m] * P[row][m]
    {
        const int r = t >> 3, k = t & 7;
        const int row = tr * 32 + r;
        float a = 0.f;
#pragma unroll
        for (int m = 0; m < R; ++m) a += sb[k * 8 + m] * P[(size_t)row * R + m];
        tsh[r][k] = 2.0f * a;
    }
    __syncthreads();

    const int lr0 = wave * 8;
#pragma unroll
    for (int rr = 0; rr < 8; ++rr) {
        const int row = tr * 32 + lr0 + rr;
        const float* tv = &tsh[lr0 + rr][0];
        float t0 = tv[0], t1 = tv[1], t2 = tv[2], t3 = tv[3];
        float t4 = tv[4], t5 = tv[5], t6 = tv[6], t7 = tv[7];
        float4 w4 = W4[(size_t)row * (DIM / 4) + c4];
        float o[4];
#pragma unroll
        for (int jj = 0; jj < 4; ++jj) {
            float d = t0 * alo[jj].x + t1 * alo[jj].y +
                      t2 * alo[jj].z + t3 * alo[jj].w +
                      t4 * ahi[jj].x + t5 * ahi[jj].y +
                      t6 * ahi[jj].z + t7 * ahi[jj].w;
            o[jj] = ((const float*)&w4)[jj] - d;
        }
        O4[(size_t)row * (DIM / 4) + c4] = make_float4(o[0], o[1], o[2], o[3]);
    }
}

extern "C" void kernel_launch(void* const* d_in, const int* in_sizes, int n_in,
                              void* d_out, int out_size, void* d_ws, size_t ws_size,
                              hipStream_t stream) {
    const float* W = (const float*)d_in[0];    // [4096][4096] f32
    const float* A = (const float*)d_in[1];    // [4096][8]    f32
    float* out = (float*)d_out;                // [4096][4096] f32
    float* G = (float*)d_ws;                   // 64 floats (8x8 Gram)
    float* P = (float*)d_ws + P_OFF;           // 4096*8 floats

    dot_kernel<<<DIM / 4 + 2, 256, 0, stream>>>(W, A, G, P);
    apply_kernel<<<2048, 256, 0, stream>>>(W, A, G, P, out);
}

// Round 7
// 60.117 us; speedup vs baseline: 2.6673x; 1.0415x over previous
//
#include <hip/hip_runtime.h>

#define DIM 4096
#define R 8
// ws layout: G (8x8) at ws[0..63]; P2 (4096 rows x 2 halves x 8) at ws+64
#define P_OFF 64

// ---------------------------------------------------------------------------
// K1: blocks 0,1 = Gram rows 0..3 / 4..7 (dispatched first, overlaps).
// Blocks 2..2049: P2[row][ch][:] = W[row, ch-half] @ A[ch-half, :]
// (4 rows x 2048 cols per block, plain stores to disjoint slots).
// ---------------------------------------------------------------------------
__global__ __launch_bounds__(256) void dot_kernel(const float* __restrict__ W,
                                                  const float* __restrict__ A,
                                                  float* __restrict__ G,
                                                  float* __restrict__ P2) {
    __shared__ float red[4][32];
    const int t = threadIdx.x;
    const int wave = t >> 6, lane = t & 63;
    const int bid = blockIdx.x;
    const float4* W4 = (const float4*)W;
    const float4* A4 = (const float4*)A;

    if (bid < 2) {
        // ---- Gram path: block 0 -> G rows 0..3, block 1 -> rows 4..7
        const int hi = bid * 4;  // 0 or 4 (block-uniform)
        float p[4][R];
#pragma unroll
        for (int r = 0; r < 4; ++r)
#pragma unroll
            for (int k = 0; k < R; ++k) p[r][k] = 0.f;

        for (int it = 0; it < DIM / 256; ++it) {
            const int j = it * 256 + t;
            float4 alo = A4[j * 2 + 0];
            float4 ahi = A4[j * 2 + 1];
            float u[R] = {alo.x, alo.y, alo.z, alo.w, ahi.x, ahi.y, ahi.z, ahi.w};
            float wv0 = hi ? u[4] : u[0];
            float wv1 = hi ? u[5] : u[1];
            float wv2 = hi ? u[6] : u[2];
            float wv3 = hi ? u[7] : u[3];
#pragma unroll
            for (int k = 0; k < R; ++k) {
                p[0][k] += wv0 * u[k];
                p[1][k] += wv1 * u[k];
                p[2][k] += wv2 * u[k];
                p[3][k] += wv3 * u[k];
            }
        }

#pragma unroll
        for (int r = 0; r < 4; ++r)
#pragma unroll
            for (int k = 0; k < R; ++k) {
                float v = p[r][k];
#pragma unroll
                for (int off = 32; off >= 1; off >>= 1) v += __shfl_xor(v, off, 64);
                p[r][k] = v;
            }

#pragma unroll
        for (int i = 0; i < 32; ++i)
            if (lane == i) red[wave][i] = p[i / R][i % R];
        __syncthreads();

        if (t < 32) {
            float v = red[0][t] + red[1][t] + red[2][t] + red[3][t];
            G[(hi + (t >> 3)) * 8 + (t & 7)] = v;
        }
        return;
    }

    // ---- dot path: 4 rows x half the columns; all 8 W-loads upfront
    const int db = bid - 2;          // 0..2047
    const int row0 = (db >> 1) * 4;
    const int ch = db & 1;           // column half

    float4 w[2][4];
#pragma unroll
    for (int c = 0; c < 2; ++c)
#pragma unroll
        for (int r = 0; r < 4; ++r)
            w[c][r] = W4[(size_t)(row0 + r) * (DIM / 4) + ch * 512 + c * 256 + t];

    float p[4][R];
#pragma unroll
    for (int r = 0; r < 4; ++r)
#pragma unroll
        for (int k = 0; k < R; ++k) p[r][k] = 0.f;

#pragma unroll
    for (int c = 0; c < 2; ++c) {
#pragma unroll
        for (int jj = 0; jj < 4; ++jj) {
            const int j = (ch * 512 + c * 256 + t) * 4 + jj;
            float4 alo = A4[j * 2 + 0];
            float4 ahi = A4[j * 2 + 1];
#pragma unroll
            for (int r = 0; r < 4; ++r) {
                const float wv = ((const float*)&w[c][r])[jj];
                p[r][0] += wv * alo.x; p[r][1] += wv * alo.y;
                p[r][2] += wv * alo.z; p[r][3] += wv * alo.w;
                p[r][4] += wv * ahi.x; p[r][5] += wv * ahi.y;
                p[r][6] += wv * ahi.z; p[r][7] += wv * ahi.w;
            }
        }
    }

#pragma unroll
    for (int r = 0; r < 4; ++r)
#pragma unroll
        for (int k = 0; k < R; ++k) {
            float v = p[r][k];
#pragma unroll
            for (int off = 32; off >= 1; off >>= 1) v += __shfl_xor(v, off, 64);
            p[r][k] = v;
        }

#pragma unroll
    for (int i = 0; i < 32; ++i)
        if (lane == i) red[wave][i] = p[i / R][i % R];
    __syncthreads();

    if (t < 32) {
        float v = red[0][t] + red[1][t] + red[2][t] + red[3][t];
        P2[((size_t)(row0 + (t >> 3)) * 2 + ch) * R + (t & 7)] = v;
    }
}

// ---------------------------------------------------------------------------
// K2: out = W - (2 (P0+P1) G^{-1}) . A^T.  2048 blocks x 256 threads.
// Wave 0 inverts G (8x8 Gauss-Jordan) hidden under A-fragment loads.
// ---------------------------------------------------------------------------
__global__ __launch_bounds__(256, 4) void apply_kernel(const float* __restrict__ W,
                                                       const float* __restrict__ A,
                                                       const float* __restrict__ G,
                                                       const float* __restrict__ P2,
                                                       float* __restrict__ out) {
    __shared__ float sb[64];       // Sinv = G^{-1}
    __shared__ float tsh[32][8];

    const int t = threadIdx.x;
    const int wave = t >> 6, lane = t & 63;
    const int bid = blockIdx.x;
    const int tr = bid >> 4;        // 128 row-tiles of 32
    const int tc = bid & 15;        // 16 col-tiles of 256
    const int c4 = tc * 64 + lane;  // float4 column index [0,1024)

    const float4* A4 = (const float4*)A;
    const float4* W4 = (const float4*)W;
    float4* O4 = (float4*)out;

    // issue A-fragment loads first (independent, hides the GJ below)
    float4 alo[4], ahi[4];
#pragma unroll
    for (int jj = 0; jj < 4; ++jj) {
        const int j = c4 * 4 + jj;
        alo[jj] = A4[j * 2 + 0];
        ahi[jj] = A4[j * 2 + 1];
    }

    if (wave == 0) {
        const int r_ = lane >> 3, c_ = lane & 7;
        float M = G[lane];
        float E = (r_ == c_) ? 1.f : 0.f;
        // Gauss-Jordan, no pivoting (G is SPD, kappa ~ 1)
#pragma unroll
        for (int k = 0; k < R; ++k) {
            float piv  = __shfl(M, k * 8 + k, 64);
            float pinv = 1.0f / piv;
            float Mkc  = __shfl(M, k * 8 + c_, 64) * pinv;
            float Ekc  = __shfl(E, k * 8 + c_, 64) * pinv;
            float Mrk  = __shfl(M, r_ * 8 + k, 64);
            bool  isk  = (r_ == k);
            M = isk ? Mkc : (M - Mrk * Mkc);
            E = isk ? Ekc : (E - Mrk * Ekc);
        }
        sb[lane] = E;
    }
    __syncthreads();

    // one t-value per thread: t[r][k] = 2 * sum_m Sinv[k][m] * (P0+P1)[row][m]
    {
        const int r = t >> 3, k = t & 7;
        const int row = tr * 32 + r;
        const float* p0 = &P2[(size_t)row * 2 * R];
        float a = 0.f;
#pragma unroll
        for (int m = 0; m < R; ++m) a += sb[k * 8 + m] * (p0[m] + p0[R + m]);
        tsh[r][k] = 2.0f * a;
    }
    __syncthreads();

    const int lr0 = wave * 8;
#pragma unroll
    for (int rr = 0; rr < 8; ++rr) {
        const int row = tr * 32 + lr0 + rr;
        const float* tv = &tsh[lr0 + rr][0];
        float t0 = tv[0], t1 = tv[1], t2 = tv[2], t3 = tv[3];
        float t4 = tv[4], t5 = tv[5], t6 = tv[6], t7 = tv[7];
        float4 w4 = W4[(size_t)row * (DIM / 4) + c4];
        float o[4];
#pragma unroll
        for (int jj = 0; jj < 4; ++jj) {
            float d = t0 * alo[jj].x + t1 * alo[jj].y +
                      t2 * alo[jj].z + t3 * alo[jj].w +
                      t4 * ahi[jj].x + t5 * ahi[jj].y +
                      t6 * ahi[jj].z + t7 * ahi[jj].w;
            o[jj] = ((const float*)&w4)[jj] - d;
        }
        O4[(size_t)row * (DIM / 4) + c4] = make_float4(o[0], o[1], o[2], o[3]);
    }
}

extern "C" void kernel_launch(void* const* d_in, const int* in_sizes, int n_in,
                              void* d_out, int out_size, void* d_ws, size_t ws_size,
                              hipStream_t stream) {
    const float* W = (const float*)d_in[0];    // [4096][4096] f32
    const float* A = (const float*)d_in[1];    // [4096][8]    f32
    float* out = (float*)d_out;                // [4096][4096] f32
    float* G = (float*)d_ws;                   // 64 floats (8x8 Gram)
    float* P2 = (float*)d_ws + P_OFF;          // 4096*2*8 floats

    dot_kernel<<<2 * (DIM / 4) + 2, 256, 0, stream>>>(W, A, G, P2);
    apply_kernel<<<2048, 256, 0, stream>>>(W, A, G, P2, out);
}